// Round 9
// baseline (503.503 us; speedup 1.0000x reference)
//
#include <hip/hip_runtime.h>

typedef _Float16 f16;
typedef f16 f16x2 __attribute__((ext_vector_type(2)));
typedef f16 f16x8 __attribute__((ext_vector_type(8)));
typedef float f32x4 __attribute__((ext_vector_type(4)));
typedef float f32x2 __attribute__((ext_vector_type(2)));

#define MFMA16(a, b, c) __builtin_amdgcn_mfma_f32_16x16x32_f16((a), (b), (c), 0, 0, 0)

static __device__ __forceinline__ f16x8 cvt8(const float* __restrict__ p) {
    f32x4 p0 = *(const f32x4*)p;
    f32x4 p1 = *(const f32x4*)(p + 4);
    f16x8 a;
    a[0] = (f16)p0[0]; a[1] = (f16)p0[1]; a[2] = (f16)p0[2]; a[3] = (f16)p0[3];
    a[4] = (f16)p1[0]; a[5] = (f16)p1[1]; a[6] = (f16)p1[2]; a[7] = (f16)p1[3];
    return a;
}

// Depth-bucket lookup for a sorted position i (recs order). Returns node or -1.
static __device__ __forceinline__ int sorted_node(int i, const int* __restrict__ dcnt,
                                                  const int4* __restrict__ recs, int N) {
    int o1 = dcnt[0], o2 = o1 + dcnt[1], o3 = o2 + dcnt[2], o4 = o3 + dcnt[3];
    int dI, off;
    if (i < o1)      { dI = 0; off = 0; }
    else if (i < o2) { dI = 1; off = o1; }
    else if (i < o3) { dI = 2; off = o2; }
    else if (i < o4) { dI = 3; off = o3; }
    else return -1;
    return recs[(size_t)dI * N + (i - off)].x;
}

// Fused prep: blocks [0,48) repack weights; [48,48+CB) count in-degrees AND
// out-degrees; rest classify nodes by depth into recs[].x.
__global__ __launch_bounds__(256) void k_prep(
        const float* __restrict__ pw, const float* __restrict__ mw1,
        const float* __restrict__ mw2, const float* __restrict__ uw1,
        const float* __restrict__ uw2,
        f16* __restrict__ pwp, f16* __restrict__ mw1p, f16* __restrict__ mw2p,
        f16* __restrict__ uw1p, f16* __restrict__ uw2p,
        const int* __restrict__ ei, int* __restrict__ degv, int* __restrict__ odeg,
        const int* __restrict__ dep, int* __restrict__ dcnt,
        int4* __restrict__ recs, int CB, int E, int N) {
    __shared__ int lcnt[4];
    __shared__ int lbase[4];
    int b = blockIdx.x;
    int t = threadIdx.x;
    if (b < 48) {
        const float* W; f16* out; int fb;
        if (b < 8)       { W = pw;  out = pwp;  fb = b; }
        else if (b < 16) { W = mw1; out = mw1p; fb = b - 8; }
        else if (b < 24) { W = mw2; out = mw2p; fb = b - 16; }
        else if (b < 40) { W = uw1; out = uw1p; fb = b - 24; }
        else             { W = uw2; out = uw2p; fb = b - 40; }
        int idx = fb * 256 + t;
        int lane = idx & 63;
        int nt = (idx >> 6) & 7;
        int kt = idx >> 9;
        int colx = lane & 15, quad = lane >> 4;
        f16* o = out + (size_t)idx * 8;
        const float* wb = W + (size_t)(kt * 32 + quad * 8) * 128 + nt * 16 + colx;
#pragma unroll
        for (int j = 0; j < 8; j++) o[j] = (f16)wb[(size_t)j * 128];
    } else if (b < 48 + CB) {
        int e = (b - 48) * 256 + t;
        if (e < E) {
            atomicAdd(&degv[ei[E + e]], 1);
            atomicAdd(&odeg[ei[e]], 1);
        }
    } else {
        if (t < 4) lcnt[t] = 0;
        __syncthreads();
        int v = (b - 48 - CB) * 256 + t;
        int d = (v < N) ? dep[v] : 0;
        int p = -1;
        if (d >= 1 && d <= 4) p = atomicAdd(&lcnt[d - 1], 1);
        __syncthreads();
        if (t < 4) lbase[t] = (lcnt[t] > 0) ? atomicAdd(&dcnt[t], lcnt[t]) : 0;
        __syncthreads();
        if (d >= 1 && d <= 4) recs[(size_t)(d - 1) * N + lbase[d - 1] + p].x = v;
    }
}

// Blocks [0,2*SB): scan stage A for BOTH scans (sorted-dst sums, then src
// sums) into one bsum[2*SB]. Rest: proj — h = x@pw+pb; t = h@mw1[0:128]+mb1.
__global__ __launch_bounds__(256) void k_mid(
        const int* __restrict__ degv, const int* __restrict__ odeg,
        const int4* __restrict__ recs, const int* __restrict__ dcnt,
        int* __restrict__ bsum, int SB,
        const float* __restrict__ x, const f16* __restrict__ pwp,
        const f16* __restrict__ mw1p, const float* __restrict__ pb,
        const float* __restrict__ mb1, float* __restrict__ h,
        f16* __restrict__ hh, f16* __restrict__ t, int N) {
    __shared__ __align__(16) f16 lds[4][16 * 136];
    __shared__ int wsum[4];
    int tid = threadIdx.x;
    if ((int)blockIdx.x < 2 * SB) {
        int bb = blockIdx.x;
        int v = 0;
        if (bb < SB) {
            int i = bb * 256 + tid;
            int node = sorted_node(i, dcnt, recs, N);
            if (node >= 0) v = degv[node];
        } else {
            int i = (bb - SB) * 256 + tid;
            v = (i < N) ? odeg[i] : 0;
        }
#pragma unroll
        for (int off = 32; off; off >>= 1) v += __shfl_down(v, off, 64);
        if ((tid & 63) == 0) wsum[tid >> 6] = v;
        __syncthreads();
        if (tid == 0) bsum[bb] = wsum[0] + wsum[1] + wsum[2] + wsum[3];
        return;
    }
    int lane = tid & 63, w = tid >> 6;
    int colx = lane & 15, quad = lane >> 4;
    int base = ((blockIdx.x - 2 * SB) * 4 + w) * 16;
    int arow = base + colx;
    int u = arow < N ? arow : N - 1;

    f32x4 c1[8];
#pragma unroll
    for (int nt = 0; nt < 8; nt++) c1[nt] = (f32x4){0.f, 0.f, 0.f, 0.f};
#pragma unroll
    for (int kt = 0; kt < 4; kt++) {
        f16x8 a = cvt8(x + (size_t)u * 128 + kt * 32 + quad * 8);
#pragma unroll
        for (int nt = 0; nt < 8; nt++) {
            f16x8 b = *(const f16x8*)(pwp + ((size_t)(kt * 8 + nt) * 64 + lane) * 8);
            c1[nt] = MFMA16(a, b, c1[nt]);
        }
    }
#pragma unroll
    for (int nt = 0; nt < 8; nt++) {
        float bias = pb[nt * 16 + colx];
#pragma unroll
        for (int reg = 0; reg < 4; reg++) {
            int row = quad * 4 + reg;
            int node = base + row;
            float v = c1[nt][reg] + bias;
            lds[w][row * 136 + nt * 16 + colx] = (f16)v;
            if (node < N) {
                h[(size_t)node * 128 + nt * 16 + colx] = v;
                hh[(size_t)node * 128 + nt * 16 + colx] = (f16)v;
            }
        }
    }
    f32x4 c2[8];
#pragma unroll
    for (int nt = 0; nt < 8; nt++) c2[nt] = (f32x4){0.f, 0.f, 0.f, 0.f};
#pragma unroll
    for (int kt = 0; kt < 4; kt++) {
        f16x8 a = *(const f16x8*)&lds[w][colx * 136 + kt * 32 + quad * 8];
#pragma unroll
        for (int nt = 0; nt < 8; nt++) {
            f16x8 b = *(const f16x8*)(mw1p + ((size_t)(kt * 8 + nt) * 64 + lane) * 8);
            c2[nt] = MFMA16(a, b, c2[nt]);
        }
    }
#pragma unroll
    for (int nt = 0; nt < 8; nt++) {
        float bias = mb1[nt * 16 + colx];
#pragma unroll
        for (int reg = 0; reg < 4; reg++) {
            int node = base + quad * 4 + reg;
            if (node < N) t[(size_t)node * 128 + nt * 16 + colx] = (f16)(c2[nt][reg] + bias);
        }
    }
}

// Dual scan: blocks [0,NBv) scan degv in DEPTH-SORTED (recs) order, writing
// rowp[node] and recs[].y/.z (= contiguous per-depth CSR ranges). Blocks
// [NBv,2*NBv) scan odeg in node order into orowp (src CSR).
__global__ __launch_bounds__(256) void k_scanC(
        const int* __restrict__ degv, const int* __restrict__ odeg,
        int4* __restrict__ recs, const int* __restrict__ dcnt,
        const int* __restrict__ bsum, int* __restrict__ rowp,
        int* __restrict__ orowp, int NBv, int N, int E) {
    __shared__ int lds[256];
    __shared__ int wo[4];
    int b = blockIdx.x, t = threadIdx.x;
    bool isSrc = b >= NBv;
    int i = (isSrc ? b - NBv : b) * 256 + t;
    int node = -1, dI = -1, joff = 0;
    int v = 0;
    if (!isSrc) {
        int o1 = dcnt[0], o2 = o1 + dcnt[1], o3 = o2 + dcnt[2], o4 = o3 + dcnt[3];
        if (i < o1)      { dI = 0; joff = 0; }
        else if (i < o2) { dI = 1; joff = o1; }
        else if (i < o3) { dI = 2; joff = o2; }
        else if (i < o4) { dI = 3; joff = o3; }
        if (dI >= 0) {
            node = recs[(size_t)dI * N + (i - joff)].x;
            v = degv[node];
        }
    } else {
        v = (i < N) ? odeg[i] : 0;
    }
    lds[t] = v;
    __syncthreads();
#pragma unroll
    for (int d = 1; d < 256; d <<= 1) {
        int u = (t >= d) ? lds[t - d] : 0;
        __syncthreads();
        lds[t] += u;
        __syncthreads();
    }
    int off = 0;
    for (int j = (isSrc ? NBv : 0) + t; j < b; j += 256) off += bsum[j];
#pragma unroll
    for (int o = 32; o; o >>= 1) off += __shfl_down(off, o, 64);
    if ((t & 63) == 0) wo[t >> 6] = off;
    __syncthreads();
    int boff = wo[0] + wo[1] + wo[2] + wo[3];
    int val = boff + lds[t] - v;
    if (!isSrc && dI >= 0) {
        rowp[node] = val;
        int4* r = &recs[(size_t)dI * N + (i - joff)];
        r->y = val;
        r->z = val + v;
    }
    if (isSrc && i < N) orowp[i] = val;
    if (isSrc && b == NBv && t == 0) orowp[N] = E;
}

// Scatter: assign each edge its dst-CSR slot p (depth-sorted, skip depth-0
// dsts) and write a src-CSR forward record fwd[q] = {p | (dst_depth<<24), ea}
// (or x=-1 for depth-0 dsts).
__global__ __launch_bounds__(256) void k_scat(const int* __restrict__ ei,
                                              const float* __restrict__ eattr,
                                              const int* __restrict__ dep,
                                              const int* __restrict__ rowp,
                                              const int* __restrict__ orowp,
                                              int* __restrict__ cur,
                                              int* __restrict__ ocur,
                                              int2* __restrict__ fwd,
                                              int E, int N) {
    int gtid = blockIdx.x * 256 + threadIdx.x;
    int gsz = gridDim.x * 256;
    for (int e = gtid; e < E; e += gsz) {
        int s = ei[e], dn = ei[E + e];
        int dd = dep[dn];
        int px = -1;
        if (dd >= 1) {
            int p = rowp[dn] + atomicAdd(&cur[dn], 1);
            px = p | (dd << 24);
        }
        int q = orowp[s] + atomicAdd(&ocur[s], 1);
        fwd[q] = (int2){px, __float_as_int(eattr[e])};
    }
}

// Stage 1 (per depth): src-major msg-precompute. Iterates srcs in node order
// (t reads = sequential stream), computes a_e = relu(t[src] + ea*w1row) in
// f16 (bit-identical to the old build_afr), scatter-stores 256-B rows to
// msgbuf[p]. Stores are fire-and-forget -> not bound by the gather-latency
// wall that pinned k_md at 47.5 us. tOrg/tUpd select: dep(src)-1 < dIdx.
__global__ __launch_bounds__(256) void k_msg(
        const f16* __restrict__ tOrg, const f16* __restrict__ tUpd,
        const float* __restrict__ mw1, const int* __restrict__ dep,
        const int* __restrict__ orowp, const int2* __restrict__ fwd,
        f16* __restrict__ msgbuf, int dIdx, int N) {
    const int lane = threadIdx.x & 63;
    const int gw = blockIdx.x * 4 + (threadIdx.x >> 6);
    const int nw = gridDim.x * 4;
    const float* w1r = mw1 + 128 * 128;
    f32x2 wq = *(const f32x2*)(w1r + lane * 2);
    f16 w0 = (f16)wq[0], w1 = (f16)wq[1];
    const int want = dIdx + 1;

    for (int s = gw; s < N; s += nw) {
        int q0 = orowp[s], q1 = orowp[s + 1];
        if (q0 == q1) continue;
        int ds = dep[s];
        const f16* tb = ((unsigned)(ds - 1) < (unsigned)dIdx) ? tUpd : tOrg;
        f16x2 tv = *(const f16x2*)(tb + (size_t)s * 128 + lane * 2);
        for (int q = q0; q < q1; q++) {
            int2 f = fwd[q];
            if (f.x >= 0 && (f.x >> 24) == want) {
                f16 ea = (f16)__int_as_float(f.y);
                f16 a0 = tv[0] + ea * w0;
                f16 a1 = tv[1] + ea * w1;
                a0 = a0 > (f16)0 ? a0 : (f16)0;
                a1 = a1 > (f16)0 ? a1 : (f16)0;
                f16x2 a = {a0, a1};
                *(f16x2*)(msgbuf + (size_t)(f.x & 0xFFFFFF) * 128 + lane * 2) = a;
            }
        }
    }
}

// Stage 2 (per depth): v7's k_md with the random t-gather replaced by a
// CONTIGUOUS msgbuf stream (depth-sorted CSR => each block's rounds read a
// contiguous window). No ebuf/eah/w1h — afr rows come pre-activated from
// k_msg. 2 barriers/round (was 3). Update phase identical to v7.
__global__ __launch_bounds__(512) void k_md(
        const f16* __restrict__ msgbuf, const float* __restrict__ mb2,
        const f16* __restrict__ mw2p,
        const int4* __restrict__ recs, const int* __restrict__ dcnt,
        const f16* __restrict__ hh, const f16* __restrict__ uw1p,
        const f16* __restrict__ uw2p, const f16* __restrict__ mw1p,
        const float* __restrict__ ub1, const float* __restrict__ ub2,
        const float* __restrict__ mb1, float* __restrict__ h,
        f16* __restrict__ tUpd, int dIdx, int N) {
    __shared__ __align__(16) f16 bsm[128 * 128];     // 32 KB staged mw2p
    __shared__ __align__(16) f16 tbuf[8][16][136];   // 34 KB staged msg rows
    __shared__ __align__(16) f16 pool[16][136];      // agg, then c2-out
    __shared__ __align__(16) f16 sout[16][136];      // c1-out
    __shared__ int ids[16], se0[16], se1[16];
    f16* hbuf = &tbuf[0][0][0];  // hh tile [16][136]; tbuf dead after msg

    const int tid = threadIdx.x;
    const int lane = tid & 63;
    const int w = tid >> 6;                 // wave 0..7
    const int colx = lane & 15, quad = lane >> 4;
    const int cnt = dcnt[dIdx];

    {
        const f16x8* s8 = (const f16x8*)mw2p;
        f16x8* d8 = (f16x8*)bsm;
#pragma unroll
        for (int i = 0; i < 4; i++) d8[i * 512 + tid] = s8[i * 512 + tid];
    }
    float mb2v[8];
#pragma unroll
    for (int nt = 0; nt < 8; nt++) mb2v[nt] = mb2[nt * 16 + colx];

    const int b = blockIdx.x, nb = gridDim.x;
    const int s0 = (int)((long long)cnt * b / nb);
    const int s1 = (int)((long long)cnt * (b + 1) / nb);

    __syncthreads();  // bsm ready

    for (int cs = s0; cs < s1; cs += 16) {
        int cc = s1 - cs; if (cc > 16) cc = 16;
        if (tid < 16) {
            if (tid < cc) {
                int4 r = recs[(size_t)dIdx * N + cs + tid];
                ids[tid] = r.x; se0[tid] = r.y; se1[tid] = r.z;
            } else {
                ids[tid] = 0; se0[tid] = 0; se1[tid] = 0;
            }
        }
        __syncthreads();

        // ---- msg phase: 2 groups of 8 nodes
        for (int g = 0; g < 2; g++) {
            int maxT = 0;
#pragma unroll
            for (int s = 0; s < 8; s++) {
                int r = g * 8 + s;
                int tc = (se1[r] - se0[r] + 15) >> 4;
                if (tc > maxT) maxT = tc;
            }
            float aggv[8] = {0.f, 0.f, 0.f, 0.f, 0.f, 0.f, 0.f, 0.f};
            for (int rd = 0; rd < maxT; rd++) {
                // contiguous stream: 2048 16-B loads from msgbuf windows
#pragma unroll
                for (int it = 0; it < 4; it++) {
                    int task = it * 512 + tid;
                    int row = task >> 4, seg = task & 15;
                    int s = row >> 4, j = row & 15;
                    int r = g * 8 + s;
                    int es = se0[r] + rd * 16 + j;
                    if (es < se1[r]) {
                        *(f16x8*)&tbuf[s][j][seg * 8] =
                            *(const f16x8*)(msgbuf + (size_t)es * 128 + seg * 8);
                    }
                }
                __syncthreads();
                // compute: wave w handles node g*8+w from LDS
                {
                    int r = g * 8 + w;
                    int bs = se0[r] + rd * 16;
                    int rem = se1[r] - bs;
                    if (rem > 0) {
                        f16x8 afr[4];
#pragma unroll
                        for (int kt = 0; kt < 4; kt++)
                            afr[kt] = *(const f16x8*)&tbuf[w][colx][kt * 32 + quad * 8];
#pragma unroll
                        for (int nt = 0; nt < 8; nt++) {
                            f32x4 c = (f32x4){0.f, 0.f, 0.f, 0.f};
#pragma unroll
                            for (int kt = 0; kt < 4; kt++) {
                                f16x8 bb = *(const f16x8*)&bsm[((kt * 8 + nt) * 64 + lane) * 8];
                                c = MFMA16(afr[kt], bb, c);
                            }
#pragma unroll
                            for (int reg = 0; reg < 4; reg++)
                                if (quad * 4 + reg < rem)
                                    aggv[nt] += fmaxf(c[reg] + mb2v[nt], 0.f);
                        }
                    }
                }
                __syncthreads();  // protect tbuf before next round
            }
            {
                int r = g * 8 + w;
                int deg = se1[r] - se0[r];
                float inv = 1.f / (float)(deg > 1 ? deg : 1);
#pragma unroll
                for (int nt = 0; nt < 8; nt++) {
                    float s = aggv[nt];
                    s += __shfl_xor(s, 16, 64);
                    s += __shfl_xor(s, 32, 64);
                    if (quad == 0) pool[r][nt * 16 + colx] = (f16)(s * inv);
                }
            }
        }
        __syncthreads();  // pool complete; tbuf free for hh staging

        if (tid < 256) {
            int row = tid >> 4, seg = tid & 15;
            *(f16x8*)&hbuf[row * 136 + seg * 8] =
                *(const f16x8*)(hh + (size_t)ids[row] * 128 + seg * 8);
        }
        __syncthreads();

        // ---- update phase: wave w owns nt = w
        f32x4 c1 = (f32x4){0.f, 0.f, 0.f, 0.f};
#pragma unroll
        for (int kt = 0; kt < 8; kt++) {
            f16x8 a;
            if (kt < 4)
                a = *(const f16x8*)&hbuf[colx * 136 + kt * 32 + quad * 8];
            else
                a = *(const f16x8*)&pool[colx][(kt - 4) * 32 + quad * 8];
            f16x8 bb = *(const f16x8*)(uw1p + ((size_t)(kt * 8 + w) * 64 + lane) * 8);
            c1 = MFMA16(a, bb, c1);
        }
        {
            float bias = ub1[w * 16 + colx];
#pragma unroll
            for (int reg = 0; reg < 4; reg++) {
                int row = quad * 4 + reg;
                sout[row][w * 16 + colx] = (f16)fmaxf(c1[reg] + bias, 0.f);
            }
        }
        __syncthreads();
        f32x4 c2 = (f32x4){0.f, 0.f, 0.f, 0.f};
#pragma unroll
        for (int kt = 0; kt < 4; kt++) {
            f16x8 a = *(const f16x8*)&sout[colx][kt * 32 + quad * 8];
            f16x8 bb = *(const f16x8*)(uw2p + ((size_t)(kt * 8 + w) * 64 + lane) * 8);
            c2 = MFMA16(a, bb, c2);
        }
        {
            float bias = ub2[w * 16 + colx];
#pragma unroll
            for (int reg = 0; reg < 4; reg++) {
                int row = quad * 4 + reg;
                float v = fmaxf(c2[reg] + bias, 0.f);
                pool[row][w * 16 + colx] = (f16)v;
                if (row < cc)
                    h[(size_t)ids[row] * 128 + w * 16 + colx] = v;
            }
        }
        __syncthreads();
        if (dIdx < 3) {
            f32x4 c3 = (f32x4){0.f, 0.f, 0.f, 0.f};
#pragma unroll
            for (int kt = 0; kt < 4; kt++) {
                f16x8 a = *(const f16x8*)&pool[colx][kt * 32 + quad * 8];
                f16x8 bb = *(const f16x8*)(mw1p + ((size_t)(kt * 8 + w) * 64 + lane) * 8);
                c3 = MFMA16(a, bb, c3);
            }
            float bias = mb1[w * 16 + colx];
#pragma unroll
            for (int reg = 0; reg < 4; reg++) {
                int row = quad * 4 + reg;
                if (row < cc)
                    tUpd[(size_t)ids[row] * 128 + w * 16 + colx] =
                        (f16)(c3[reg] + bias);
            }
        }
        __syncthreads();
    }
}

extern "C" void kernel_launch(void* const* d_in, const int* in_sizes, int n_in,
                              void* d_out, int out_size, void* d_ws, size_t ws_size,
                              hipStream_t stream) {
    const float* x    = (const float*)d_in[0];
    const int*   ei   = (const int*)d_in[1];
    const float* eatt = (const float*)d_in[2];
    const int*   dep  = (const int*)d_in[3];
    const float* pw   = (const float*)d_in[4];
    const float* pb   = (const float*)d_in[5];
    const float* mw1  = (const float*)d_in[6];
    const float* mb1  = (const float*)d_in[7];
    const float* mw2  = (const float*)d_in[8];
    const float* mb2  = (const float*)d_in[9];
    const float* uw1  = (const float*)d_in[10];
    const float* ub1  = (const float*)d_in[11];
    const float* uw2  = (const float*)d_in[12];
    const float* ub2  = (const float*)d_in[13];
    float* h = (float*)d_out;

    int N = in_sizes[3];
    int E = in_sizes[1] / 2;
    int NB = (N + 255) / 256;
    int CB = (E + 255) / 256;

    char* ws = (char*)d_ws;
    size_t o = 0;
    auto alloc = [&](size_t bytes) -> char* {
        char* p = ws + o;
        o += (bytes + 255) & ~(size_t)255;
        return p;
    };
    f16*   t    = (f16*)alloc((size_t)N * 128 * 2);   // tOrg
    f16*   hh   = (f16*)alloc((size_t)N * 128 * 2);
    f16*   tUpd = (f16*)alloc((size_t)N * 128 * 2);
    char*  z0   = (char*)alloc(0);
    int*   degv = (int*)alloc((size_t)N * 4);
    int*   odeg = (int*)alloc((size_t)N * 4);
    int*   cur  = (int*)alloc((size_t)N * 4);
    int*   ocur = (int*)alloc((size_t)N * 4);
    int*   dcnt = (int*)alloc(64);
    size_t zbytes = (size_t)((char*)alloc(0) - z0);
    int*   rowp  = (int*)alloc((size_t)(N + 1) * 4);
    int*   orowp = (int*)alloc((size_t)(N + 1) * 4);
    int*   bsum  = (int*)alloc((size_t)2 * NB * 4);
    int2*  fwd   = (int2*)alloc((size_t)E * 8);
    int4*  recs  = (int4*)alloc((size_t)4 * N * 16);
    f16*   pwp  = (f16*)alloc(128 * 128 * 2);
    f16*   mw1p = (f16*)alloc(128 * 128 * 2);
    f16*   mw2p = (f16*)alloc(128 * 128 * 2);
    f16*   uw1p = (f16*)alloc(256 * 128 * 2);
    f16*   uw2p = (f16*)alloc(128 * 128 * 2);
    f16*   msgbuf = (f16*)alloc((size_t)E * 128 * 2 + 8192);  // ~128 MB

    hipMemsetAsync(z0, 0, zbytes, stream);

    k_prep<<<48 + CB + NB, 256, 0, stream>>>(pw, mw1, mw2, uw1, uw2,
                                             pwp, mw1p, mw2p, uw1p, uw2p,
                                             ei, degv, odeg, dep, dcnt, recs,
                                             CB, E, N);
    int PB = (N + 63) / 64;
    k_mid<<<2 * NB + PB, 256, 0, stream>>>(degv, odeg, recs, dcnt, bsum, NB,
                                           x, pwp, mw1p, pb, mb1, h, hh, t, N);
    k_scanC<<<2 * NB, 256, 0, stream>>>(degv, odeg, recs, dcnt, bsum,
                                        rowp, orowp, NB, N, E);
    k_scat<<<CB, 256, 0, stream>>>(ei, eatt, dep, rowp, orowp, cur, ocur,
                                   fwd, E, N);

    for (int d = 0; d < 4; d++) {
        k_msg<<<2048, 256, 0, stream>>>(t, tUpd, mw1, dep, orowp, fwd,
                                        msgbuf, d, N);
        k_md<<<512, 512, 0, stream>>>(msgbuf, mb2, mw2p, recs, dcnt,
                                      hh, uw1p, uw2p, mw1p, ub1, ub2, mb1, h,
                                      tUpd, d, N);
    }
}